// Round 15
// baseline (4794.038 us; speedup 1.0000x reference)
//
#include <hip/hip_runtime.h>
#include <hip/hip_bf16.h>

#define B 32
#define S 512
#define H 1024
#define G 4096          // 4*H
#define NBLK 256
#define HSLOT 65536     // shorts per h slot (2 dirs x B x H)

typedef __attribute__((ext_vector_type(8))) short bf16x8;
typedef __attribute__((ext_vector_type(8))) unsigned short u16x8;
typedef __attribute__((ext_vector_type(4))) float f32x4;

__device__ __forceinline__ unsigned short f2bf(float v) {
    __hip_bfloat16 b = __float2bfloat16(v);
    return *reinterpret_cast<unsigned short*>(&b);
}
__device__ __forceinline__ float bf2f(unsigned short u) {
    union { float f; unsigned int i; } v; v.i = ((unsigned int)u) << 16; return v.f;
}
#define MFMA(a, b, c) __builtin_amdgcn_mfma_f32_16x16x32_bf16(a, b, c, 0, 0, 0)
#define ALOAD(p)    __hip_atomic_load((p),  __ATOMIC_RELAXED, __HIP_MEMORY_SCOPE_AGENT)
#define ASTORE(p,v) __hip_atomic_store((p), (v), __ATOMIC_RELAXED, __HIP_MEMORY_SCOPE_AGENT)

// =====================================================================
// prep_weights: fragment-ordered bf16 weights for one matrix pair (fw,bw).
// chunk idx = ((blk*4 + w)*16 + f)*64 + lane, 8 bf16/chunk; 1,048,576 chunks.
// =====================================================================
__global__ __launch_bounds__(256)
void prep_weights(const float* __restrict__ fw, const float* __restrict__ bw,
                  unsigned short* __restrict__ dst)
{
    size_t idx = (size_t)blockIdx.x * 256 + threadIdx.x;
    int lane = idx & 63;
    int f    = (idx >> 6) & 15;
    int w    = (idx >> 10) & 3;
    int blk  = (int)(idx >> 12);
    int dir  = blk >> 7, jg = blk & 127;
    int ks = f >> 1, ct = f & 1;

    int c  = ct * 16 + (lane & 15);
    int g  = (c >> 3) * H + jg * 8 + (c & 7);
    int kk = w * 256 + ks * 32 + ((lane >> 4) * 8);

    const float* src = dir ? bw : fw;
    u16x8 o;
#pragma unroll
    for (int i = 0; i < 8; ++i)
        o[i] = f2bf(src[(size_t)(kk + i) * G + g]);
    *(u16x8*)&dst[idx * 8] = o;
}

__global__ __launch_bounds__(256)
void prep_x(const float* __restrict__ x, unsigned short* __restrict__ xbf)
{
    size_t i8 = ((size_t)blockIdx.x * 256 + threadIdx.x) * 8;
    float4 v0 = *(const float4*)&x[i8];
    float4 v1 = *(const float4*)&x[i8 + 4];
    u16x8 o;
    o[0] = f2bf(v0.x); o[1] = f2bf(v0.y); o[2] = f2bf(v0.z); o[3] = f2bf(v0.w);
    o[4] = f2bf(v1.x); o[5] = f2bf(v1.y); o[6] = f2bf(v1.z); o[7] = f2bf(v1.w);
    *(u16x8*)&xbf[i8] = o;
}

// =====================================================================
// lstm_persist: one cooperative kernel, all 512 steps.
// 256 blocks x 512 threads. Block (dir,jg) owns 32 gate-cols.
// Sync protocol (SENTINEL DATA-POLL — no flags, no mailbox, no acks):
//  - hhist slots 1..S are pre-filled with 0xFF bytes. An 8B chunk equal
//    to ~0ull is "not yet written" (4x bf16 NaN — unreachable by real h,
//    which is tanh-bounded). 8B stores are single-copy atomic.
//  - producer gate waves fire packed 8B h-stores and move on (no vmcnt).
//  - consumer U-wave polls exactly the 32 8B chunks per lane it needs;
//    when a chunk != sentinel it IS the data, already in registers —
//    detect and load are the same operation. Quarter-granular skew
//    absorption is automatic (each wave waits only on its own slice).
// Datapath (R9/R10/R14-proven): U frags in LDS; W-waves free-run x@W
// into 8-slot LDS ring paced by gcnt (bumped at ring-consume time);
// dout via nontemporal stores.
// =====================================================================
__global__ __launch_bounds__(512, 1)
void lstm_persist(const unsigned short* __restrict__ wbufU,
                  const unsigned short* __restrict__ wbufW,
                  const unsigned short* __restrict__ xbf,
                  unsigned short* __restrict__ hhist,  // 513 slots x HSLOT
                  const float* __restrict__ pad,
                  const float* __restrict__ bfw, const float* __restrict__ bbw,
                  float* __restrict__ dout)
{
    const int blk = blockIdx.x;
    const int dir = blk >> 7;
    const int jg  = blk & 127;
    const int j0  = jg * 8;
    const int tid = threadIdx.x;
    const int wave = tid >> 6;
    const int lane = tid & 63;

    __shared__ short Uw[32768];                  // 64 KB U frags (wave-local regions)
    __shared__ float red[4][2][16][33];          // U partials
    __shared__ unsigned short ring[8][32][36];   // xz lookahead (bf16, bias folded)
    __shared__ unsigned rcnt;                    // red arrivals (monotone, 4/step)
    __shared__ unsigned gcnt;                    // ring consumes (monotone, 4/step)
    __shared__ int ring_ready[8];                // slot generation = fs+1

    if (tid == 0) { rcnt = 0; gcnt = 0; }
    if (tid < 8) ring_ready[tid] = 0;
    __syncthreads();   // the only block-wide barrier (init)

    const int arow  = lane & 15;
    const int akoff = (lane >> 4) * 8;
    const int drow  = (lane >> 4) * 4;
    const int dcol  = lane & 15;
    const float* bsrc = dir ? bbw : bfw;
    const float wb0 = bsrc[(dcol >> 3) * H + j0 + (dcol & 7)];
    const float wb1 = bsrc[(((16 + dcol) >> 3)) * H + j0 + ((16 + dcol) & 7)];

    if (wave < 4) {
        // ---- load this wave's U region into LDS (16 KB, wave-local) ----
        {
            const unsigned short* src = wbufU + (((size_t)blk * 4 + wave) * 16) * 512 + lane * 8;
#pragma unroll
            for (int f = 0; f < 16; ++f)
                *(u16x8*)&Uw[((wave * 16 + f) * 64 + lane) * 8] = *(const u16x8*)(src + f * 512);
        }

        float hst = 0.f, cst = 0.f;
        const int gb  = (tid >> 3) & 31;
        const int gj  = tid & 7;
        const int gbt = gb >> 4, grow = gb & 15;
        const f32x4 zero4 = {0.f, 0.f, 0.f, 0.f};
        const unsigned long long SENT = ~0ull;

        for (int t = 0; t < S; ++t) {
            const int s = dir ? (S - 1 - t) : t;
            float pv = pad[gb * S + s];      // early issue, hidden under poll

            // ---- sentinel data-poll: this wave's h(t-1) slice ----
            // per lane: 32 x 8B chunks (16 for rows arow, 16 for arow+16)
            const unsigned long long* hb64 = (const unsigned long long*)
                (hhist + (size_t)t * HSLOT
                       + ((size_t)(dir * B) + arow) * H + wave * 256 + akoff);
            const unsigned long long* hb64b = hb64 + 4 * H;   // +16*H shorts
            unsigned long long v[32];
            unsigned missing = 0xffffffffu;
            for (;;) {
#pragma unroll
                for (int i = 0; i < 16; ++i) {
                    if (missing & (1u << i))
                        v[i] = ALOAD(hb64 + (i >> 1) * 8 + (i & 1));
                    if (missing & (1u << (16 + i)))
                        v[16 + i] = ALOAD(hb64b + (i >> 1) * 8 + (i & 1));
                }
#pragma unroll
                for (int i = 0; i < 32; ++i)
                    if ((missing & (1u << i)) && v[i] != SENT)
                        missing &= ~(1u << i);
                if (!__any((int)(missing != 0u))) break;
                __builtin_amdgcn_s_sleep(1);
            }

            // ---- U phase: h(t-1) @ U — data already in registers ----
            f32x4 u00 = zero4, u01 = zero4, u10 = zero4, u11 = zero4;
#pragma unroll
            for (int ks = 0; ks < 8; ++ks) {
                union { unsigned long long q[2]; bf16x8 x; } ua0, ua1;
                ua0.q[0] = v[2 * ks];      ua0.q[1] = v[2 * ks + 1];
                ua1.q[0] = v[16 + 2 * ks]; ua1.q[1] = v[16 + 2 * ks + 1];
                bf16x8 b0 = *(const bf16x8*)&Uw[((wave * 16 + ks * 2 + 0) * 64 + lane) * 8];
                bf16x8 b1 = *(const bf16x8*)&Uw[((wave * 16 + ks * 2 + 1) * 64 + lane) * 8];
                u00 = MFMA(ua0.x, b0, u00); u01 = MFMA(ua0.x, b1, u01);
                u10 = MFMA(ua1.x, b0, u10); u11 = MFMA(ua1.x, b1, u11);
            }
#pragma unroll
            for (int r = 0; r < 4; ++r) {
                red[wave][0][drow + r][dcol]      = u00[r];
                red[wave][0][drow + r][16 + dcol] = u01[r];
                red[wave][1][drow + r][dcol]      = u10[r];
                red[wave][1][drow + r][16 + dcol] = u11[r];
            }
            asm volatile("s_waitcnt lgkmcnt(0)" ::: "memory");
            if (lane == 0) atomicAdd(&rcnt, 1u);
            {
                const unsigned need = 4u * (unsigned)(t + 1);
                while (*(volatile unsigned*)&rcnt < need) {}
                asm volatile("" ::: "memory");
            }

            // ---- ring slot t (normally ready 4+ steps ago) ----
            while (*(volatile int*)&ring_ready[t & 7] < t + 1) {}
            asm volatile("" ::: "memory");

            // ---- gate ----
            float z[4];
#pragma unroll
            for (int q = 0; q < 4; ++q) {
                const int c = q * 8 + gj;
                float zz = bf2f(ring[t & 7][gb][c]);
#pragma unroll
                for (int w = 0; w < 4; ++w) zz += red[w][gbt][grow][c];
                z[q] = zz;
            }
            // ring slot consumed -> free it for W-waves (off publish path)
            asm volatile("s_waitcnt lgkmcnt(0)" ::: "memory");
            if (lane == 0) atomicAdd(&gcnt, 1u);

            float ig = 1.f / (1.f + expf(-z[0]));
            float fg = 1.f / (1.f + expf(-z[1]));
            float gg = tanhf(z[2]);
            float og = 1.f / (1.f + expf(-z[3]));

            float m  = 1.f - pv;
            float cn = fg * cst + ig * gg;
            float hn = og * tanhf(cn);
            float h2 = fmaf(m, hn - hst, hst);
            float c2 = fmaf(m, cn - cst, cst);
            hst = h2; cst = c2;

            // ---- publish h(t) -> hhist[t+1]: fire-and-forget 8B stores ----
            unsigned u = (unsigned)f2bf(h2);
            const int gl = lane & ~3;
            unsigned v0 = (unsigned)__shfl((int)u, gl + 0);
            unsigned v1 = (unsigned)__shfl((int)u, gl + 1);
            unsigned v2 = (unsigned)__shfl((int)u, gl + 2);
            unsigned v3 = (unsigned)__shfl((int)u, gl + 3);
            if ((lane & 3) == 0) {
                unsigned long long pk = (unsigned long long)(v0 & 0xffffu)
                                      | ((unsigned long long)(v1 & 0xffffu) << 16)
                                      | ((unsigned long long)(v2 & 0xffffu) << 32)
                                      | ((unsigned long long)(v3 & 0xffffu) << 48);
                unsigned long long* hp = (unsigned long long*)
                    (hhist + (size_t)(t + 1) * HSLOT
                           + ((size_t)(dir * B) + gb) * H + j0 + gj);
                ASTORE(hp, pk);
            }

            // ---- dout (nontemporal, off every sync path) ----
            __builtin_nontemporal_store(h2,
                &dout[((size_t)gb * S + s) * (2 * H) + dir * H + j0 + gj]);
            if (t == S - 1) {
                size_t base = (size_t)B * S * 2 * H;
                __builtin_nontemporal_store(h2,
                    &dout[base + dir * 2 * B * H + gb * H + j0 + gj]);
                __builtin_nontemporal_store(c2,
                    &dout[base + dir * 2 * B * H + B * H + gb * H + j0 + gj]);
            }
        }
    } else {
        // ---- W waves: free-running xz producer, fs = wave-4, +4 ----
        const f32x4 zero4 = {0.f, 0.f, 0.f, 0.f};
        for (int fs = wave - 4; fs < S; fs += 4) {
            if (fs >= 8) {   // wait until gate consumed slot (step fs-8 read)
                const unsigned need = 4u * (unsigned)(fs - 7);
                while (*(volatile unsigned*)&gcnt < need)
                    __builtin_amdgcn_s_sleep(2);   // coarse: >=4-step slack
                asm volatile("" ::: "memory");
            }
            const int s2 = dir ? (S - 1 - fs) : fs;
            f32x4 a00 = zero4, a01 = zero4, a10 = zero4, a11 = zero4;
            for (int sl = 0; sl < 4; ++sl) {
                const unsigned short* wbase =
                    wbufW + (((size_t)blk * 4 + sl) * 16) * 512 + lane * 8;
                bf16x8 wf[16];
#pragma unroll
                for (int f = 0; f < 16; ++f) wf[f] = *(const bf16x8*)(wbase + f * 512);
                const unsigned short* A0 =
                    xbf + ((size_t)arow * S + s2) * H + sl * 256 + akoff;
#pragma unroll
                for (int ks = 0; ks < 8; ++ks) {
                    bf16x8 x0 = *(const bf16x8*)(A0 + ks * 32);
                    bf16x8 x1 = *(const bf16x8*)(A0 + (size_t)16 * S * H + ks * 32);
                    a00 = MFMA(x0, wf[ks*2+0], a00); a01 = MFMA(x0, wf[ks*2+1], a01);
                    a10 = MFMA(x1, wf[ks*2+0], a10); a11 = MFMA(x1, wf[ks*2+1], a11);
                }
            }
            const int slot = fs & 7;
#pragma unroll
            for (int r = 0; r < 4; ++r) {
                ring[slot][drow + r][dcol]           = f2bf(a00[r] + wb0);
                ring[slot][drow + r][16 + dcol]      = f2bf(a01[r] + wb1);
                ring[slot][16 + drow + r][dcol]      = f2bf(a10[r] + wb0);
                ring[slot][16 + drow + r][16 + dcol] = f2bf(a11[r] + wb1);
            }
            asm volatile("s_waitcnt lgkmcnt(0)" ::: "memory");
            if (lane == 0) *(volatile int*)&ring_ready[slot] = fs + 1;
        }
    }
}

// =====================================================================
// Host side
// =====================================================================
extern "C" void kernel_launch(void* const* d_in, const int* in_sizes, int n_in,
                              void* d_out, int out_size, void* d_ws, size_t ws_size,
                              hipStream_t stream)
{
    const float* x   = (const float*)d_in[0];
    const float* pad = (const float*)d_in[1];
    const float* Wfw = (const float*)d_in[2];
    const float* Ufw = (const float*)d_in[3];
    const float* bfw = (const float*)d_in[4];
    const float* Wbw = (const float*)d_in[5];
    const float* Ubw = (const float*)d_in[6];
    const float* bbw = (const float*)d_in[7];
    float* out = (float*)d_out;

    char* w = (char*)d_ws;
    unsigned short* wbufW = (unsigned short*)w;                     // 16.8 MB
    unsigned short* wbufU = wbufW + (size_t)1048576 * 8;            // 16.8 MB
    unsigned short* xbf   = wbufU + (size_t)1048576 * 8;            // 33.6 MB
    unsigned short* hhist = xbf + (size_t)B * S * H;                // 513 x 128 KB

    // slot 0 = initial h = zeros; slots 1..S = 0xFF sentinel bytes
    hipMemsetAsync(hhist, 0x00, (size_t)HSLOT * sizeof(unsigned short), stream);
    hipMemsetAsync(hhist + (size_t)HSLOT, 0xFF,
                   (size_t)S * HSLOT * sizeof(unsigned short), stream);

    prep_x<<<8192, 256, 0, stream>>>(x, xbf);
    prep_weights<<<4096, 256, 0, stream>>>(Wfw, Wbw, wbufW);
    prep_weights<<<4096, 256, 0, stream>>>(Ufw, Ubw, wbufU);

    void* args[] = { (void*)&wbufU, (void*)&wbufW, (void*)&xbf, (void*)&hhist,
                     (void*)&pad, (void*)&bfw, (void*)&bbw, (void*)&out };
    hipLaunchCooperativeKernel((void*)lstm_persist, dim3(NBLK), dim3(512),
                               args, 0, stream);
}